// Round 1
// baseline (761.465 us; speedup 1.0000x reference)
//
#include <hip/hip_runtime.h>
#include <cmath>
#include <complex>
#include <cstring>

#define N_T   300
#define N_TS  270
#define N_W   29
#define N_B   32
#define SLICE 5184            // 72*72
#define N_SLICES (N_B * N_T * 3)   // 28800
#define G_ELEMS (N_T * N_T)        // 90000

// ---------------- Kernel 1: spatial mean over 72x72 ----------------
// One wave (64 lanes) per slice, 4 slices per 256-thread block.
// 5184 floats = 1296 float4 = 20*64 + 16: fully-unrolled 20x float4 loads
// per lane -> 20 loads in flight per wave, no LDS, no __syncthreads.
__global__ __launch_bounds__(256) void k_spatial_mean(const float* __restrict__ x,
                                                      float* __restrict__ m) {
    const int wid  = threadIdx.x >> 6;
    const int lane = threadIdx.x & 63;
    const int slice = blockIdx.x * 4 + wid;          // grid = N_SLICES/4
    const float4* p = (const float4*)(x + (size_t)slice * SLICE);

    float s0 = 0.f, s1 = 0.f;
#pragma unroll
    for (int i = 0; i < 20; i += 2) {
        float4 v0 = p[lane + (i << 6)];
        float4 v1 = p[lane + ((i + 1) << 6)];
        s0 += (v0.x + v0.y) + (v0.z + v0.w);
        s1 += (v1.x + v1.y) + (v1.z + v1.w);
    }
    if (lane < 16) {                                  // tail: 1280..1295
        float4 v = p[1280 + lane];
        s0 += (v.x + v.y) + (v.z + v.w);
    }
    float s = s0 + s1;
#pragma unroll
    for (int off = 32; off > 0; off >>= 1) s += __shfl_down(s, off);
    if (lane == 0) m[slice] = s * (1.0f / SLICE);
}

// ---------------- Kernel 2: POS windows + overlap-add + G-matvec + minmax ----
__global__ __launch_bounds__(320) void k_phaseB(const float* __restrict__ m,
                                                const float* __restrict__ G,
                                                float* __restrict__ out) {
    int b = blockIdx.x;
    int tid = threadIdx.x;
    __shared__ __align__(16) float sm[N_T * 3];
    __shared__ __align__(16) float sPn[N_TS * N_W];
    __shared__ __align__(16) float sHs[N_T];
    __shared__ __align__(16) float sf[N_T];
    __shared__ float rmn[5], rmx[5];

    for (int i = tid; i < N_T * 3; i += 320) sm[i] = m[b * N_T * 3 + i];
    __syncthreads();

    if (tid < N_TS) {
        int t = tid;
        float cm0 = 0.f, cm1 = 0.f, cm2 = 0.f;
#pragma unroll
        for (int w = 0; w < N_W; w++) {
            cm0 += sm[(t + w) * 3 + 0];
            cm1 += sm[(t + w) * 3 + 1];
            cm2 += sm[(t + w) * 3 + 2];
        }
        cm0 *= (1.f / N_W); cm1 *= (1.f / N_W); cm2 *= (1.f / N_W);
        float r0 = 1.f / cm0, r1 = 1.f / cm1, r2 = 1.f / cm2;
        float S0[N_W], S1[N_W];
        float m0 = 0.f, m1 = 0.f;
#pragma unroll
        for (int w = 0; w < N_W; w++) {
            float c0 = sm[(t + w) * 3 + 0] * r0;
            float c1 = sm[(t + w) * 3 + 1] * r1;
            float c2 = sm[(t + w) * 3 + 2] * r2;
            S0[w] = c1 - c2;                 // Pm row 0: [0,1,-1]
            S1[w] = c1 + c2 - 2.f * c0;      // Pm row 1: [-2,1,1]
            m0 += S0[w]; m1 += S1[w];
        }
        m0 *= (1.f / N_W); m1 *= (1.f / N_W);
        float v0 = 0.f, v1 = 0.f;
#pragma unroll
        for (int w = 0; w < N_W; w++) {
            float d0 = S0[w] - m0, d1 = S1[w] - m1;
            v0 += d0 * d0; v1 += d1 * d1;
        }
        float alpha = sqrtf(v0 / v1);        // std0/std1, ddof=0
        float pm = 0.f;
#pragma unroll
        for (int w = 0; w < N_W; w++) { S0[w] += alpha * S1[w]; pm += S0[w]; }
        pm *= (1.f / N_W);
        float pv = 0.f;
#pragma unroll
        for (int w = 0; w < N_W; w++) { float d = S0[w] - pm; pv += d * d; }
        float is = 1.0f / sqrtf(pv * (1.f / N_W));
#pragma unroll
        for (int w = 0; w < N_W; w++) sPn[t * N_W + w] = (S0[w] - pm) * is;
    }
    __syncthreads();

    // Overlap-add as a gather: Hs[s] = sum_w Pn[s-w, w] for valid t=s-w
    if (tid < N_T) {
        int s = tid;
        int wlo = max(0, s - (N_TS - 1));
        int whi = min(N_W - 1, s);
        float acc = 0.f;
        for (int w = wlo; w <= whi; w++) acc += sPn[(s - w) * N_W + w];
        sHs[s] = acc;
    }
    __syncthreads();

    // f = G * Hs  (G fuses detrend + filtfilt, precomputed on host)
    if (tid < N_T) {
        int s = tid;
        const float4* g = (const float4*)(G + s * N_T);
        const float4* h = (const float4*)sHs;
        float acc = 0.f;
#pragma unroll 5
        for (int j = 0; j < N_T / 4; j++) {
            float4 gv = g[j], hv = h[j];
            acc += gv.x * hv.x + gv.y * hv.y + gv.z * hv.z + gv.w * hv.w;
        }
        sf[s] = acc;
    }
    __syncthreads();

    float mn = 3.0e38f, mx = -3.0e38f;
    if (tid < N_T) { mn = sf[tid]; mx = sf[tid]; }
    for (int off = 32; off > 0; off >>= 1) {
        mn = fminf(mn, __shfl_down(mn, off));
        mx = fmaxf(mx, __shfl_down(mx, off));
    }
    int wid = tid >> 6, lane = tid & 63;
    if (lane == 0) { rmn[wid] = mn; rmx[wid] = mx; }
    __syncthreads();
    mn = fminf(fminf(fminf(rmn[0], rmn[1]), fminf(rmn[2], rmn[3])), rmn[4]);
    mx = fmaxf(fmaxf(fmaxf(rmx[0], rmx[1]), fmaxf(rmx[2], rmx[3])), rmx[4]);
    float inv = 1.0f / (mx - mn);
    if (tid < N_T) out[b * N_T + tid] = (sf[tid] - mn) * inv;
}

// ---------------- Host: build G = F_filtfilt * (I - A^{-1}) in double --------
static void lfilter_h(const double* b, const double* a, const double* zi,
                      double z0scale, const double* x, double* y, int n) {
    double z[5];
    for (int k = 0; k < 5; k++) z[k] = zi[k] * z0scale;
    for (int t = 0; t < n; t++) {
        double xt = x[t];
        double yt = b[0] * xt + z[0];
        z[0] = z[1] + b[1] * xt - a[1] * yt;
        z[1] = z[2] + b[2] * xt - a[2] * yt;
        z[2] = z[3] + b[3] * xt - a[3] * yt;
        z[3] = b[4] * xt - a[4] * yt + z[4];
        z[4] = b[5] * xt - a[5] * yt;
        y[t] = yt;
    }
}

static void filtfilt_h(const double* b, const double* a, const double* zi,
                       const double* x, double* out) {
    const int N = N_T, P = 18, E = N_T + 2 * 18;
    double ext[N_T + 36], y1[N_T + 36], y2[N_T + 36], tmp[N_T + 36];
    for (int i = 0; i < P; i++) ext[i] = 2.0 * x[0] - x[P - i];
    for (int i = 0; i < N; i++) ext[P + i] = x[i];
    for (int i = 0; i < P; i++) ext[P + N + i] = 2.0 * x[N - 1] - x[N - 2 - i];
    lfilter_h(b, a, zi, ext[0], ext, y1, E);
    for (int i = 0; i < E; i++) tmp[i] = y1[E - 1 - i];
    lfilter_h(b, a, zi, tmp[0], tmp, y2, E);
    for (int i = 0; i < N; i++) out[i] = y2[E - 1 - (P + i)];
}

static void compute_constants(float* hostG) {
    // --- butter(5, 0.2), bilinear transform, exactly as reference numpy ---
    const int order = 5;
    double b[6], a[6];
    {
        std::complex<double> p[5];
        for (int k = 1; k <= 5; k++) {
            double theta = M_PI * (2.0 * k + order - 1.0) / (2.0 * order);
            p[k - 1] = std::exp(std::complex<double>(0.0, theta));
        }
        double fs = 2.0;
        double wn = 3.0 / (30.0 / 2.0);  // CUTOFF/(FS/2) = 0.2
        double warped = 2.0 * fs * std::tan(M_PI * wn / fs);
        double kg = std::pow(warped, 5.0);
        double fs2 = 2.0 * fs;
        std::complex<double> pz[5], prod = 1.0;
        for (int k = 0; k < 5; k++) {
            std::complex<double> pw = warped * p[k];
            pz[k] = (fs2 + pw) / (fs2 - pw);
            prod *= (fs2 - pw);
        }
        double kz = kg * std::real(1.0 / prod);
        const double binom[6] = {1, 5, 10, 10, 5, 1};
        for (int i = 0; i < 6; i++) b[i] = kz * binom[i];
        std::complex<double> c[6];
        c[0] = 1.0; for (int i = 1; i < 6; i++) c[i] = 0.0;
        for (int k = 0; k < 5; k++)
            for (int j = k + 1; j >= 1; j--) c[j] = c[j] - pz[k] * c[j - 1];
        for (int i = 0; i < 6; i++) a[i] = std::real(c[i]);
        // reference casts b,a to float32
        for (int i = 0; i < 6; i++) { b[i] = (double)(float)b[i]; a[i] = (double)(float)a[i]; }
    }
    // --- lfilter_zi: solve (I - comp.T) zi = B ---
    double zi[5];
    {
        double T[5][6];
        for (int i = 0; i < 5; i++) {
            for (int j = 0; j < 5; j++) {
                double compT = (j == 0) ? (-a[i + 1]) : ((i == j - 1) ? 1.0 : 0.0);
                T[i][j] = ((i == j) ? 1.0 : 0.0) - compT;
            }
            T[i][5] = b[i + 1] - a[i + 1] * b[0];
        }
        for (int col = 0; col < 5; col++) {             // gaussian elim, partial pivot
            int piv = col;
            for (int rr = col + 1; rr < 5; rr++)
                if (std::fabs(T[rr][col]) > std::fabs(T[piv][col])) piv = rr;
            if (piv != col) for (int j = 0; j < 6; j++) { double t = T[col][j]; T[col][j] = T[piv][j]; T[piv][j] = t; }
            for (int rr = 0; rr < 5; rr++) {
                if (rr == col) continue;
                double f = T[rr][col] / T[col][col];
                for (int j = col; j < 6; j++) T[rr][j] -= f * T[col][j];
            }
        }
        for (int i = 0; i < 5; i++) zi[i] = T[i][5] / T[i][i];
        for (int i = 0; i < 5; i++) zi[i] = (double)(float)zi[i];  // reference fp32 cast
    }
    // --- banded A = I + lam^2 D^T D (pentadiagonal, bw 2), Cholesky ---
    double Ab0[N_T], Ab1[N_T], Ab2[N_T];
    for (int i = 0; i < N_T; i++) { Ab0[i] = 1.0; Ab1[i] = 0.0; Ab2[i] = 0.0; }
    {
        const double v[3] = {1.0, -2.0, 1.0};
        const double lam2 = 100.0 * 100.0;
        for (int r = 0; r < N_T - 2; r++)
            for (int pq = 0; pq < 3; pq++)
                for (int q = pq; q < 3; q++) {
                    int j = r + pq, d = q - pq;
                    double val = lam2 * v[pq] * v[q];
                    if (d == 0) Ab0[j] += val;
                    else if (d == 1) Ab1[j] += val;
                    else Ab2[j] += val;
                }
    }
    double l0[N_T], l1[N_T], l2[N_T];
    for (int i = 0; i < N_T; i++) {
        l2[i] = (i >= 2) ? Ab2[i - 2] / l0[i - 2] : 0.0;
        l1[i] = (i >= 1) ? (Ab1[i - 1] - l2[i] * l1[i - 1]) / l0[i - 1] : 0.0;
        l0[i] = std::sqrt(Ab0[i] - l1[i] * l1[i] - l2[i] * l2[i]);
    }
    // --- per basis column: M e_i = e_i - A^{-1} e_i, then filtfilt it ---
    double yf[N_T], u[N_T], Mcol[N_T], g[N_T];
    for (int i = 0; i < N_T; i++) {
        for (int j = 0; j < N_T; j++) {
            double rhs = (j == i) ? 1.0 : 0.0;
            if (j >= 1) rhs -= l1[j] * yf[j - 1];
            if (j >= 2) rhs -= l2[j] * yf[j - 2];
            yf[j] = rhs / l0[j];
        }
        for (int j = N_T - 1; j >= 0; j--) {
            double rhs = yf[j];
            if (j + 1 < N_T) rhs -= l1[j + 1] * u[j + 1];
            if (j + 2 < N_T) rhs -= l2[j + 2] * u[j + 2];
            u[j] = rhs / l0[j];
        }
        for (int j = 0; j < N_T; j++)
            Mcol[j] = (double)(float)(((j == i) ? 1.0 : 0.0) - u[j]);  // reference stores M in fp32
        filtfilt_h(b, a, zi, Mcol, g);
        for (int s = 0; s < N_T; s++) hostG[s * N_T + i] = (float)g[s];
    }
}

extern "C" void kernel_launch(void* const* d_in, const int* in_sizes, int n_in,
                              void* d_out, int out_size, void* d_ws, size_t ws_size,
                              hipStream_t stream) {
    static float* hostG = nullptr;
    if (!hostG) {
        if (hipHostMalloc((void**)&hostG, G_ELEMS * sizeof(float), hipHostMallocDefault)
            != hipSuccess)
            hostG = new float[G_ELEMS];   // pageable fallback
    }
    compute_constants(hostG);  // deterministic; recomputed every call (same values)

    float* wsf = (float*)d_ws;
    float* dG = wsf;                 // 90000 floats
    float* dm = wsf + G_ELEMS;       // 28800 floats

    const float* x = (const float*)d_in[0];
    float* out = (float*)d_out;

    hipMemcpyAsync(dG, hostG, G_ELEMS * sizeof(float), hipMemcpyHostToDevice, stream);
    k_spatial_mean<<<N_SLICES / 4, 256, 0, stream>>>(x, dm);
    k_phaseB<<<N_B, 320, 0, stream>>>(dm, dG, out);
}